// Round 3
// baseline (266.018 us; speedup 1.0000x reference)
//
#include <hip/hip_runtime.h>

// Problem constants (match setup_inputs in the reference)
#define B_   16
#define R_   16
#define T_   4
#define S_   14
#define NPRB 273
#define NPD  6      // pilots per DMRS symbol per PRB (subcarrier positions)
#define NDS  2      // number of DMRS OFDM symbols
#define RE_  12     // resource elements per PRB
#define P_   (NDS*NPRB*NPD)   // 3276 pilots total
#define NSC  (NPRB*RE_)       // 3276 subcarriers
#define F_   (RE_*S_)         // 168 grid positions per tx

#define NH   (B_*T_*NSC*S_*R_)   // 46964736 floats (h_full)
#define NPE  (T_*NSC*S_*2)       // 366912 floats (pe)
#define NH4  (NH/4)
#define NPE4 (NPE/4)
#define NTOT4 (NH4+NPE4)

// native Clang vector type — accepted by __builtin_nontemporal_store
typedef float vf4 __attribute__((ext_vector_type(4)));

// -------------------------------------------------------------------------
// Kernel A (tiny, 1 block, 256 threads): per tx t and flat grid index f
// (reference lays the flat [RE*S] table out re-major: re = f/S, s = f%S):
//   qtab[t][f]        = ds*NPRB*NPD + (sc & ~1)   (even FOCC-pair base)
//   pe_base[t][f][0]  = normalized min time-distance  (channels swapped, as ref)
//   pe_base[t][f][1]  = normalized min freq-distance
// mean/std (ddof=1) per tx via 64-lane butterfly reductions, one wave per tx.
// -------------------------------------------------------------------------
__global__ __launch_bounds__(256) void prep_tables(
    const int* __restrict__ ofdm_pos,     // [T_,NDS]
    const int* __restrict__ sc_pos,       // [T_,NPD]
    int* __restrict__ qtab,               // [T_*F_]
    float* __restrict__ pe_base)          // [T_*F_*2]
{
    __shared__ float dt_sh[T_*F_];
    __shared__ float df_sh[T_*F_];
    __shared__ float stats[T_][4]; // mean_t, inv_std_t, mean_f, inv_std_f
    __shared__ int   sc_sh[T_*NPD];
    __shared__ int   of_sh[T_*NDS];

    const int tid = threadIdx.x;
    if (tid < T_*NPD) sc_sh[tid] = sc_pos[tid];
    if (tid < T_*NDS) of_sh[tid] = ofdm_pos[tid];
    __syncthreads();

    for (int e = tid; e < T_*F_; e += 256) {
        const int t = e / F_, f = e % F_;
        const int re = f / S_, s = f % S_;   // reference's re-major flat layout
        int best = 1 << 30, bestj = 0;
        int dfmin = 1 << 30, dtmin = 1 << 30;
        #pragma unroll
        for (int sci = 0; sci < NPD; ++sci) {
            const int dsc = abs(re - sc_sh[t*NPD + sci]);
            if (dsc < dfmin) dfmin = dsc;
            #pragma unroll
            for (int ofi = 0; ofi < NDS; ++ofi) {
                const int dof = abs(s - of_sh[t*NDS + ofi]);
                const int d = dsc + dof;
                // strict < keeps the FIRST minimum (jnp.argmin tie-break)
                if (d < best) { best = d; bestj = sci*NDS + ofi; }
            }
        }
        #pragma unroll
        for (int ofi = 0; ofi < NDS; ++ofi) {
            const int dof = abs(s - of_sh[t*NDS + ofi]);
            if (dof < dtmin) dtmin = dof;
        }
        const int sc = bestj / NDS, ds = bestj % NDS;
        qtab[e] = ds*(NPRB*NPD) + (sc & ~1);
        dt_sh[e] = (float)dtmin;
        df_sh[e] = (float)dfmin;
    }
    __syncthreads();

    // one wave (64 lanes) per tx: butterfly mean, then butterfly var
    const int w = tid >> 6, lane = tid & 63;   // 4 waves, w == tx
    {
        float st = 0.f, sf = 0.f;
        for (int i = lane; i < F_; i += 64) { st += dt_sh[w*F_+i]; sf += df_sh[w*F_+i]; }
        #pragma unroll
        for (int off = 32; off >= 1; off >>= 1) {
            st += __shfl_xor(st, off);
            sf += __shfl_xor(sf, off);
        }
        const float mt = st / (float)F_, mf = sf / (float)F_;
        float vt = 0.f, vf = 0.f;
        for (int i = lane; i < F_; i += 64) {
            const float a = dt_sh[w*F_+i] - mt; vt += a*a;
            const float b = df_sh[w*F_+i] - mf; vf += b*b;
        }
        #pragma unroll
        for (int off = 32; off >= 1; off >>= 1) {
            vt += __shfl_xor(vt, off);
            vf += __shfl_xor(vf, off);
        }
        if (lane == 0) {
            const float stdt = sqrtf(vt / (float)(F_-1));  // ddof=1
            const float stdf = sqrtf(vf / (float)(F_-1));
            stats[w][0] = mt; stats[w][1] = 1.0f/(stdt + 1e-8f);
            stats[w][2] = mf; stats[w][3] = 1.0f/(stdf + 1e-8f);
        }
    }
    __syncthreads();

    for (int e = tid; e < T_*F_; e += 256) {
        const int t = e / F_;
        // channel order swapped exactly as in the reference: [time, freq]
        pe_base[e*2 + 0] = (dt_sh[e] - stats[t][0]) * stats[t][1];
        pe_base[e*2 + 1] = (df_sh[e] - stats[t][2]) * stats[t][3];
    }
}

// -------------------------------------------------------------------------
// Kernel B: one thread per output float4. Tables staged in LDS per block.
// h path: two cache-hit vf4 loads (FOCC pair) + average, nontemporal
// coalesced vf4 store (output is never re-read; keep L2 for h_hat_ls).
// -------------------------------------------------------------------------
__global__ __launch_bounds__(256) void gather_kernel(
    const float* __restrict__ hls,     // h_hat_ls [B_, P_, T_, R_]
    const int* __restrict__ qtab,      // [T_*F_]
    const float* __restrict__ pe_base, // [T_*F_*2]
    float* __restrict__ out)           // h_full (NH) then pe (NPE)
{
    __shared__ int   qtab_s[T_*F_];
    __shared__ float pe_s[T_*F_*2];
    const int tid = threadIdx.x;
    for (int i = tid; i < T_*F_; i += 256)   qtab_s[i] = qtab[i];
    for (int i = tid; i < T_*F_*2; i += 256) pe_s[i]   = pe_base[i];
    __syncthreads();

    const int idx = blockIdx.x * blockDim.x + tid;
    if (idx >= NTOT4) return;
    if (idx < NH4) {
        // h_full flat float index = (((b*T_ + t)*NSC + k)*S_ + s)*R_ + r
        const int r4 = idx & 3;
        int u = idx >> 2;
        const int s = u % S_;  u /= S_;
        const int k = u % NSC; u /= NSC;
        const int t = u & (T_-1);
        const int b = u >> 2;
        const int prb = k / RE_;
        const int re  = k - prb*RE_;
        // reference's scrambled lookup: flat table index f = s*RE + re
        const int f  = s*RE_ + re;
        const int p0 = qtab_s[t*F_ + f] + prb*NPD;   // even pilot of FOCC pair
        const vf4* src = (const vf4*)hls + ((b*P_ + p0)*T_ + t)*(R_/4) + r4;
        const vf4 a = src[0];
        const vf4 c = src[T_*(R_/4)];                // pilot p0+1: +T_*R_ floats
        const vf4 o = 0.5f*(a + c);
        __builtin_nontemporal_store(o, (vf4*)out + idx);
    } else {
        // pe flat float index = ((t*NSC + i)*S_ + s)*2 + c ;
        // value depends on (t, i%RE_, s, c) only.
        const int g0 = (idx - NH4) * 4;
        vf4 o;
        #pragma unroll
        for (int u2 = 0; u2 < 4; ++u2) {
            const int g  = g0 + u2;
            const int c  = g & 1;
            const int g1 = g >> 1;
            const int s  = g1 % S_;
            const int g2 = g1 / S_;
            const int i  = g2 % NSC;
            const int t  = g2 / NSC;
            const int re = i % RE_;
            o[u2] = pe_s[(t*F_ + s*RE_ + re)*2 + c];
        }
        __builtin_nontemporal_store(o, (vf4*)(out + NH) + (idx - NH4));
    }
}

extern "C" void kernel_launch(void* const* d_in, const int* in_sizes, int n_in,
                              void* d_out, int out_size, void* d_ws, size_t ws_size,
                              hipStream_t stream) {
    // inputs: y (unused, shape only), h_hat_ls f32, dmrs_ofdm_pos i32,
    // dmrs_subcarrier_pos i32
    const float* hls  = (const float*)d_in[1];
    const int*   ofdm = (const int*)d_in[2];
    const int*   scp  = (const int*)d_in[3];
    float* out = (float*)d_out;

    int*   qtab    = (int*)d_ws;
    float* pe_base = (float*)((char*)d_ws + T_*F_*sizeof(int));

    hipLaunchKernelGGL(prep_tables, dim3(1), dim3(256), 0, stream,
                       ofdm, scp, qtab, pe_base);

    const int blocks = (NTOT4 + 255) / 256;
    hipLaunchKernelGGL(gather_kernel, dim3(blocks), dim3(256), 0, stream,
                       hls, qtab, pe_base, out);
}

// Round 4
// 265.282 us; speedup vs baseline: 1.0028x; 1.0028x over previous
//
#include <hip/hip_runtime.h>

// Problem constants (match setup_inputs in the reference)
#define B_   16
#define R_   16
#define T_   4
#define S_   14
#define NPRB 273
#define NPD  6      // pilots per DMRS symbol per PRB (subcarrier positions)
#define NDS  2      // number of DMRS OFDM symbols
#define RE_  12     // resource elements per PRB
#define P_   (NDS*NPRB*NPD)   // 3276 pilots total
#define NSC  (NPRB*RE_)       // 3276 subcarriers
#define F_   (RE_*S_)         // 168 grid positions per tx

#define NH    (B_*T_*NSC*S_*R_)   // 46964736 floats (h_full)
#define NPE   (T_*NSC*S_*2)       // 366912 floats (pe)
#define NPE4  (NPE/4)             // 91728
#define NTH   (B_*T_*NSC*S_)      // 2935296 h-threads (64B each)
#define HBLOCKS (NTH/256)         // 11466 (exact)
#define PEBLOCKS ((NPE4+255)/256) // 359

typedef float vf4 __attribute__((ext_vector_type(4)));

// -------------------------------------------------------------------------
// Kernel A (tiny, 1 block, 256 threads): per tx t and flat grid index f
// (reference lays the flat [RE*S] table out re-major: re = f/S, s = f%S):
//   qtab[t][f]        = ds*NPRB*NPD + (sc & ~1)   (even FOCC-pair base)
//   pe_base[t][f][0]  = normalized min time-distance  (channels swapped, as ref)
//   pe_base[t][f][1]  = normalized min freq-distance
// mean/std (ddof=1) per tx via 64-lane butterfly reductions, one wave per tx.
// -------------------------------------------------------------------------
__global__ __launch_bounds__(256) void prep_tables(
    const int* __restrict__ ofdm_pos,     // [T_,NDS]
    const int* __restrict__ sc_pos,       // [T_,NPD]
    int* __restrict__ qtab,               // [T_*F_]
    float* __restrict__ pe_base)          // [T_*F_*2]
{
    __shared__ float dt_sh[T_*F_];
    __shared__ float df_sh[T_*F_];
    __shared__ float stats[T_][4]; // mean_t, inv_std_t, mean_f, inv_std_f
    __shared__ int   sc_sh[T_*NPD];
    __shared__ int   of_sh[T_*NDS];

    const int tid = threadIdx.x;
    if (tid < T_*NPD) sc_sh[tid] = sc_pos[tid];
    if (tid < T_*NDS) of_sh[tid] = ofdm_pos[tid];
    __syncthreads();

    for (int e = tid; e < T_*F_; e += 256) {
        const int t = e / F_, f = e % F_;
        const int re = f / S_, s = f % S_;   // reference's re-major flat layout
        int best = 1 << 30, bestj = 0;
        int dfmin = 1 << 30, dtmin = 1 << 30;
        #pragma unroll
        for (int sci = 0; sci < NPD; ++sci) {
            const int dsc = abs(re - sc_sh[t*NPD + sci]);
            if (dsc < dfmin) dfmin = dsc;
            #pragma unroll
            for (int ofi = 0; ofi < NDS; ++ofi) {
                const int dof = abs(s - of_sh[t*NDS + ofi]);
                const int d = dsc + dof;
                // strict < keeps the FIRST minimum (jnp.argmin tie-break)
                if (d < best) { best = d; bestj = sci*NDS + ofi; }
            }
        }
        #pragma unroll
        for (int ofi = 0; ofi < NDS; ++ofi) {
            const int dof = abs(s - of_sh[t*NDS + ofi]);
            if (dof < dtmin) dtmin = dof;
        }
        const int sc = bestj / NDS, ds = bestj % NDS;
        qtab[e] = ds*(NPRB*NPD) + (sc & ~1);
        dt_sh[e] = (float)dtmin;
        df_sh[e] = (float)dfmin;
    }
    __syncthreads();

    // one wave (64 lanes) per tx: butterfly mean, then butterfly var
    const int w = tid >> 6, lane = tid & 63;   // 4 waves, w == tx
    {
        float st = 0.f, sf = 0.f;
        for (int i = lane; i < F_; i += 64) { st += dt_sh[w*F_+i]; sf += df_sh[w*F_+i]; }
        #pragma unroll
        for (int off = 32; off >= 1; off >>= 1) {
            st += __shfl_xor(st, off);
            sf += __shfl_xor(sf, off);
        }
        const float mt = st / (float)F_, mf = sf / (float)F_;
        float vt = 0.f, vf = 0.f;
        for (int i = lane; i < F_; i += 64) {
            const float a = dt_sh[w*F_+i] - mt; vt += a*a;
            const float b = df_sh[w*F_+i] - mf; vf += b*b;
        }
        #pragma unroll
        for (int off = 32; off >= 1; off >>= 1) {
            vt += __shfl_xor(vt, off);
            vf += __shfl_xor(vf, off);
        }
        if (lane == 0) {
            const float stdt = sqrtf(vt / (float)(F_-1));  // ddof=1
            const float stdf = sqrtf(vf / (float)(F_-1));
            stats[w][0] = mt; stats[w][1] = 1.0f/(stdt + 1e-8f);
            stats[w][2] = mf; stats[w][3] = 1.0f/(stdf + 1e-8f);
        }
    }
    __syncthreads();

    for (int e = tid; e < T_*F_; e += 256) {
        const int t = e / F_;
        // channel order swapped exactly as in the reference: [time, freq]
        pe_base[e*2 + 0] = (dt_sh[e] - stats[t][0]) * stats[t][1];
        pe_base[e*2 + 1] = (df_sh[e] - stats[t][2]) * stats[t][3];
    }
}

// -------------------------------------------------------------------------
// Kernel B: h-region blocks — one thread per (b,t,k,s), writing 64 B
// (4 x float4). Two contiguous 64 B pilot-row loads (FOCC pair), averaged.
// Index math + table lookup amortized 4x vs the 1-float4/thread version.
// Tail blocks write pe (1 float4/thread).
// -------------------------------------------------------------------------
__global__ __launch_bounds__(256) void gather_kernel(
    const float* __restrict__ hls,     // h_hat_ls [B_, P_, T_, R_]
    const int* __restrict__ qtab,      // [T_*F_]
    const float* __restrict__ pe_base, // [T_*F_*2]
    float* __restrict__ out)           // h_full (NH) then pe (NPE)
{
    const int tid = threadIdx.x;
    const int bid = blockIdx.x;
    if (bid < HBLOCKS) {
        // h path: idx in [0, NTH) = (b,t,k,s)
        const int idx = bid*256 + tid;
        int u = idx;
        const int s = u % S_;  u /= S_;
        const int k = u % NSC; u /= NSC;
        const int t = u & (T_-1);
        const int b = u >> 2;
        const int prb = k / RE_;
        const int re  = k - prb*RE_;
        // reference's scrambled lookup: flat table index f = s*RE + re
        const int f  = s*RE_ + re;
        const int p0 = qtab[t*F_ + f] + prb*NPD;   // even pilot of FOCC pair
        const vf4* src = (const vf4*)hls + ((b*P_ + p0)*T_ + t)*(R_/4);
        vf4 a[4], c[4];
        #pragma unroll
        for (int j = 0; j < 4; ++j) a[j] = src[j];               // row p0, 64 B
        #pragma unroll
        for (int j = 0; j < 4; ++j) c[j] = src[T_*(R_/4) + j];   // row p0+1
        vf4* dst = (vf4*)out + idx*4;
        #pragma unroll
        for (int j = 0; j < 4; ++j) dst[j] = 0.5f*(a[j] + c[j]);
    } else {
        // pe path: flat float index = ((t*NSC + i)*S_ + s)*2 + c ;
        // value depends on (t, i%RE_, s, c) only.
        const int idx4 = (bid - HBLOCKS)*256 + tid;
        if (idx4 >= NPE4) return;
        const int g0 = idx4 * 4;
        vf4 o;
        #pragma unroll
        for (int u2 = 0; u2 < 4; ++u2) {
            const int g  = g0 + u2;
            const int ch = g & 1;
            const int g1 = g >> 1;
            const int s  = g1 % S_;
            const int g2 = g1 / S_;
            const int i  = g2 % NSC;
            const int t  = g2 / NSC;
            const int re = i % RE_;
            o[u2] = pe_base[(t*F_ + s*RE_ + re)*2 + ch];
        }
        ((vf4*)(out + NH))[idx4] = o;
    }
}

extern "C" void kernel_launch(void* const* d_in, const int* in_sizes, int n_in,
                              void* d_out, int out_size, void* d_ws, size_t ws_size,
                              hipStream_t stream) {
    // inputs: y (unused, shape only), h_hat_ls f32, dmrs_ofdm_pos i32,
    // dmrs_subcarrier_pos i32
    const float* hls  = (const float*)d_in[1];
    const int*   ofdm = (const int*)d_in[2];
    const int*   scp  = (const int*)d_in[3];
    float* out = (float*)d_out;

    int*   qtab    = (int*)d_ws;
    float* pe_base = (float*)((char*)d_ws + T_*F_*sizeof(int));

    hipLaunchKernelGGL(prep_tables, dim3(1), dim3(256), 0, stream,
                       ofdm, scp, qtab, pe_base);

    hipLaunchKernelGGL(gather_kernel, dim3(HBLOCKS + PEBLOCKS), dim3(256), 0,
                       stream, hls, qtab, pe_base, out);
}